// Round 6
// baseline (214.696 us; speedup 1.0000x reference)
//
#include <hip/hip_runtime.h>
#include <stdint.h>

#define CC 256
#define NNq 4096

typedef float f32x4 __attribute__((ext_vector_type(4)));
typedef short bf16x8 __attribute__((ext_vector_type(8)));

#define MFMA16(a, b, c) __builtin_amdgcn_mfma_f32_16x16x32_bf16(a, b, c, 0, 0, 0)

static __device__ __forceinline__ short f2bf(float f) {
  unsigned u = __builtin_bit_cast(unsigned, f);
  u += 0x7fffu + ((u >> 16) & 1u);   // RNE
  return (short)(u >> 16);
}
static __device__ __forceinline__ float bf2f(short s) {
  return __builtin_bit_cast(float, ((unsigned)(unsigned short)s) << 16);
}

// barrier that does NOT drain vmcnt (prefetch + stores stay in flight);
// sched_barrier(0) fences compile-time motion across it (rule 18).
#define SBAR() do { \
  __builtin_amdgcn_sched_barrier(0); \
  asm volatile("s_waitcnt lgkmcnt(0)" ::: "memory"); \
  __builtin_amdgcn_s_barrier(); \
  __builtin_amdgcn_sched_barrier(0); \
} while (0)

// ---------------------------------------------------------------------------
// Kernel 1: projections.
//  - q,k: split hi/lo bf16, separate arrays [B][N][32]; q pre-scaled by log2e.
//  - v: bf16 pre-tiled as MFMA A-fragments: v5[b][m>>5][c][m&31]
//    -> PV fragment loads are 1KB fully contiguous.
// ---------------------------------------------------------------------------
#define XSTR 66

__global__ __launch_bounds__(256) void proj_kernel(
    const float* __restrict__ x,
    const float* __restrict__ Wq, const float* __restrict__ bq,
    const float* __restrict__ Wk, const float* __restrict__ bk,
    const float* __restrict__ Wv, const float* __restrict__ bv,
    unsigned short* __restrict__ qh_, unsigned short* __restrict__ ql_,
    unsigned short* __restrict__ kh_, unsigned short* __restrict__ kl_,
    unsigned short* __restrict__ v5)
{
  __shared__ float xs[256 * XSTR];
  const int t = threadIdx.x;
  const int b = blockIdx.x >> 6;
  const int n0 = (blockIdx.x & 63) << 6;
  const float L2E = 1.4426950408889634f;

  const float* xb = x + ((size_t)b * CC) * NNq + n0;
#pragma unroll
  for (int i = 0; i < 16; ++i) {
    int fi = i * 256 + t;
    int c = fi >> 4, nv = (fi & 15) << 2;
    float4 v4 = *(const float4*)(xb + (size_t)c * NNq + nv);
    float* d = &xs[c * XSTR + nv];
    d[0] = v4.x; d[1] = v4.y; d[2] = v4.z; d[3] = v4.w;
  }
  __syncthreads();

  const int w = t >> 6, l = t & 63;
  const int l15 = l & 15, l4 = l >> 4;

  // 20 row-tiles: 16 v + 2 q + 2 k ; wave w owns tiles w*5 .. w*5+4
  f32x4 acc[5][4];
#pragma unroll
  for (int r5 = 0; r5 < 5; ++r5) {
    int rt = w * 5 + r5;
    const float* bias; float bscale;
    if (rt < 16)      { bias = bv + rt * 16;        bscale = 1.f; }
    else if (rt < 18) { bias = bq + (rt - 16) * 16; bscale = L2E; }
    else              { bias = bk + (rt - 18) * 16; bscale = 1.f; }
#pragma unroll
    for (int j = 0; j < 4; ++j) {
      float bval = bias[l4 * 4 + j] * bscale;
#pragma unroll
      for (int nt = 0; nt < 4; ++nt) acc[r5][nt][j] = bval;
    }
  }

#pragma unroll 1
  for (int ks = 0; ks < 8; ++ks) {
    bf16x8 ah[5], al[5];
#pragma unroll
    for (int r5 = 0; r5 < 5; ++r5) {
      int rt = w * 5 + r5;
      const float* wrow; float wscale;
      if (rt < 16)      { wrow = Wv + (size_t)(rt * 16 + l15) * 256;        wscale = 1.f; }
      else if (rt < 18) { wrow = Wq + (size_t)((rt - 16) * 16 + l15) * 256; wscale = L2E; }
      else              { wrow = Wk + (size_t)((rt - 18) * 16 + l15) * 256; wscale = 1.f; }
      const float* src = wrow + ks * 32 + l4 * 8;
#pragma unroll
      for (int i = 0; i < 8; ++i) {
        float v = src[i] * wscale;
        short hh = f2bf(v);
        ah[r5][i] = hh;
        al[r5][i] = f2bf(v - bf2f(hh));
      }
    }
#pragma unroll
    for (int nt = 0; nt < 4; ++nt) {
      bf16x8 bh, bl;
#pragma unroll
      for (int i = 0; i < 8; ++i) {
        float v = xs[(ks * 32 + l4 * 8 + i) * XSTR + nt * 16 + l15];
        short hh = f2bf(v);
        bh[i] = hh;
        bl[i] = f2bf(v - bf2f(hh));
      }
#pragma unroll
      for (int r5 = 0; r5 < 5; ++r5) {
        acc[r5][nt] = MFMA16(ah[r5], bl, acc[r5][nt]);
        acc[r5][nt] = MFMA16(al[r5], bh, acc[r5][nt]);
        acc[r5][nt] = MFMA16(ah[r5], bh, acc[r5][nt]);
      }
    }
  }

#pragma unroll
  for (int r5 = 0; r5 < 5; ++r5) {
    int rt = w * 5 + r5;
#pragma unroll
    for (int nt = 0; nt < 4; ++nt) {
      int n = n0 + nt * 16 + l15;
#pragma unroll
      for (int j = 0; j < 4; ++j) {
        float v = acc[r5][nt][j];
        int sub = l4 * 4 + j;
        if (rt < 16) {
          int c = rt * 16 + sub;
          // v5[b][n>>5][c][n&31]
          size_t o = (((size_t)b * 128 + (n >> 5)) * 256 + c) * 32 + (n & 31);
          v5[o] = (unsigned short)f2bf(v);
        } else {
          short hh = f2bf(v);
          short lo = f2bf(v - bf2f(hh));
          unsigned short* dh = (rt < 18) ? qh_ : kh_;
          unsigned short* dl = (rt < 18) ? ql_ : kl_;
          int d = ((rt < 18) ? (rt - 16) : (rt - 18)) * 16 + sub;
          size_t o = ((size_t)b * NNq + n) * 32 + d;
          dh[o] = (unsigned short)hh;
          dl[o] = (unsigned short)lo;
        }
      }
    }
  }
}

// ---------------------------------------------------------------------------
// Kernel 2: fused stats + attention write + PV + epilogue.
// Block = 256 threads (4 waves) owns (b, 16 rows). Grid 1024 = 4 blocks/CU:
// narrower barriers (4 waves) + 4 independent blocks/CU to overlap stalls.
// Pass 1: wave w sums exp2(e-64) over its m-quarter; LDS merge.
// Pass 2 per 64-m chunk: wave computes its 16x16 energy slice -> p(bf16) ->
//   double-buffered swizzled LDS tile -> ONE SBAR -> PV (8 MFMA, c-split
//   4 ways, v frags contiguous 1KB) + attention store FROM LDS as one
//   coalesced dwordx4 per wave (256B rows, full 128B lines, bf16->f32).
//   vmcnt never drained; stores issue after the iteration's loads so the
//   next k-wait never drains them.
// ---------------------------------------------------------------------------
__global__ __launch_bounds__(256, 4) void attn_pv_kernel(
    const unsigned short* __restrict__ qh_, const unsigned short* __restrict__ ql_,
    const unsigned short* __restrict__ kh_, const unsigned short* __restrict__ kl_,
    const unsigned short* __restrict__ v5, const float* __restrict__ x,
    const float* __restrict__ gamma, float* __restrict__ out)
{
  __shared__ __align__(16) unsigned short p_lds[2][1024]; // [par][16 n][64 m] bf16, XOR-swz
  __shared__ float sums_lds[4][16];

  const int t = threadIdx.x, w = t >> 6, l = t & 63;
  const int l15 = l & 15, l4 = l >> 4;
  // XCD swizzle: 1024 blocks (1024%8==0, bijective)
  const int sb = ((blockIdx.x & 7) << 7) | (blockIdx.x >> 3);
  const int b = sb >> 8;
  const int n0 = (sb & 255) << 4;

  const size_t qbase = ((size_t)b * NNq + n0 + l15) * 32 + l4 * 8;
  const bf16x8 qh = *(const bf16x8*)(qh_ + qbase);
  const bf16x8 qlo = *(const bf16x8*)(ql_ + qbase);
  const unsigned short* khb = kh_ + (size_t)b * NNq * 32;
  const unsigned short* klb = kl_ + (size_t)b * NNq * 32;
  const unsigned short* vbb = v5 + (size_t)b * 1048576;
  float* attn = out + 8388608 + (size_t)b * NNq * NNq + (size_t)n0 * NNq;

  // ---------------- pass 1: row sums over m-quarter w ----------------
  float sx[4] = {0.f, 0.f, 0.f, 0.f};
  {
    const int mq = w * 1024;
    bf16x8 kch[2], kcl[2];
#pragma unroll
    for (int mt = 0; mt < 2; ++mt) {
      size_t ko = (size_t)(mq + mt * 16 + l15) * 32 + l4 * 8;
      kch[mt] = *(const bf16x8*)(khb + ko);
      kcl[mt] = *(const bf16x8*)(klb + ko);
    }
#pragma unroll 1
    for (int it = 0; it < 32; ++it) {
      const int nx = mq + ((it + 1) & 31) * 32;
      bf16x8 knh[2], knl[2];
#pragma unroll
      for (int mt = 0; mt < 2; ++mt) {
        size_t ko = (size_t)(nx + mt * 16 + l15) * 32 + l4 * 8;
        knh[mt] = *(const bf16x8*)(khb + ko);
        knl[mt] = *(const bf16x8*)(klb + ko);
      }
#pragma unroll
      for (int mt = 0; mt < 2; ++mt) {
        f32x4 e = {0.f, 0.f, 0.f, 0.f};
        e = MFMA16(qh, kcl[mt], e);
        e = MFMA16(qlo, kch[mt], e);
        e = MFMA16(qh, kch[mt], e);
#pragma unroll
        for (int j = 0; j < 4; ++j) sx[j] += exp2f(e[j] - 64.0f);
      }
      kch[0] = knh[0]; kch[1] = knh[1];
      kcl[0] = knl[0]; kcl[1] = knl[1];
    }
  }
#pragma unroll
  for (int mask = 1; mask < 16; mask <<= 1)
#pragma unroll
    for (int j = 0; j < 4; ++j) sx[j] += __shfl_xor(sx[j], mask);
  if (l15 == 0) {
#pragma unroll
    for (int j = 0; j < 4; ++j) sums_lds[w][l4 * 4 + j] = sx[j];
  }
  __syncthreads();
  f32x4 crow;
#pragma unroll
  for (int j = 0; j < 4; ++j) {
    int r = l4 * 4 + j;
    crow[j] = 64.0f + log2f(sums_lds[0][r] + sums_lds[1][r] +
                            sums_lds[2][r] + sums_lds[3][r]);
  }

  // ---------------- pass 2: attention + PV ----------------
  f32x4 acc[4];   // c = w*64 + ct*16 + l4*4 + j ; n = n0 + l15
#pragma unroll
  for (int ct = 0; ct < 4; ++ct) acc[ct] = f32x4{0.f, 0.f, 0.f, 0.f};

  bf16x8 kch, kcl;
  {
    size_t ko = (size_t)(w * 16 + l15) * 32 + l4 * 8;
    kch = *(const bf16x8*)(khb + ko);
    kcl = *(const bf16x8*)(klb + ko);
  }

#pragma unroll 1
  for (int it = 0; it < 64; ++it) {
    const int mb = it * 64;
    char* pl = (char*)p_lds[it & 1];
    // v fragments for THIS chunk (contiguous 1KB per instr), issued early,
    // consumed after the barrier (energy+exp+LDS hides L2 latency)
    bf16x8 vc[4][2];
#pragma unroll
    for (int ct = 0; ct < 4; ++ct)
#pragma unroll
      for (int mh = 0; mh < 2; ++mh) {
        size_t vo = (size_t)(it * 2 + mh) * 8192 +
                    (size_t)(w * 64 + ct * 16 + l15) * 32 + l4 * 8;
        vc[ct][mh] = *(const bf16x8*)(vbb + vo);
      }
    // next-chunk k prefetch (stays in flight across the barrier)
    const int nxc = (it + 1) & 63;
    bf16x8 knh, knl;
    {
      size_t ko = (size_t)(nxc * 64 + w * 16 + l15) * 32 + l4 * 8;
      knh = *(const bf16x8*)(khb + ko);
      knl = *(const bf16x8*)(klb + ko);
    }
    // energy (one 16x16 tile per wave) -> p -> LDS tile (bf16)
    {
      f32x4 e = {0.f, 0.f, 0.f, 0.f};
      e = MFMA16(qh, kcl, e);
      e = MFMA16(qlo, kch, e);
      e = MFMA16(qh, kch, e);
#pragma unroll
      for (int j = 0; j < 4; ++j) {
        float p = exp2f(e[j] - crow[j]);
        int nl = l4 * 4 + j;                   // row within 16-tile
        int ml = w * 16 + l15;                 // m within 64-chunk
        int byteo = nl * 128 + ((ml * 2) ^ ((nl & 7) << 4));
        *(unsigned short*)(pl + byteo) = (unsigned short)f2bf(p);
      }
    }
    SBAR();
    // PV: A = v frags (regs), B = p frags from LDS (transpose read)
#pragma unroll
    for (int mh = 0; mh < 2; ++mh) {
      int o = l15 * 128 + ((mh * 64 + l4 * 16) ^ ((l15 & 7) << 4));
      bf16x8 pf = *(const bf16x8*)(pl + o);
#pragma unroll
      for (int ct = 0; ct < 4; ++ct)
        acc[ct] = MFMA16(vc[ct][mh], pf, acc[ct]);
    }
    // attention store from LDS: 1 coalesced dwordx4 per lane (256B rows)
    {
      int r = w * 4 + l4;
      int off = r * 128 + ((l15 * 8) ^ ((r & 7) << 4));
      unsigned long long v64 = *(const unsigned long long*)(pl + off);
      f32x4 pv;
#pragma unroll
      for (int i = 0; i < 4; ++i)
        pv[i] = bf2f((short)(unsigned short)(v64 >> (16 * i)));
      *(f32x4*)(attn + (size_t)r * NNq + mb + l15 * 4) = pv;
    }
    kch = knh; kcl = knl;
  }

  // epilogue: weighted = gamma*pv ; final = weighted + x
  const float gm = gamma[0];
#pragma unroll
  for (int ct = 0; ct < 4; ++ct) {
#pragma unroll
    for (int j = 0; j < 4; ++j) {
      int c = w * 64 + ct * 16 + l4 * 4 + j;
      int n = n0 + l15;
      size_t go = ((size_t)b * CC + c) * NNq + n;
      float o = acc[ct][j] * gm;
      out[4194304 + go] = o;
      out[go] = o + x[go];
    }
  }
}

extern "C" void kernel_launch(void* const* d_in, const int* in_sizes, int n_in,
                              void* d_out, int out_size, void* d_ws, size_t ws_size,
                              hipStream_t stream) {
  const float* x     = (const float*)d_in[0];
  const float* Wq    = (const float*)d_in[1];
  const float* bq    = (const float*)d_in[2];
  const float* Wk    = (const float*)d_in[3];
  const float* bk    = (const float*)d_in[4];
  const float* Wv    = (const float*)d_in[5];
  const float* bv    = (const float*)d_in[6];
  const float* gamma = (const float*)d_in[7];
  float* out = (float*)d_out;

  char* ws = (char*)d_ws;
  unsigned short* qh   = (unsigned short*)(ws);                    // 1 MB
  unsigned short* ql   = (unsigned short*)(ws + (1u << 20));       // 1 MB
  unsigned short* kh   = (unsigned short*)(ws + (2u << 20));       // 1 MB
  unsigned short* kl   = (unsigned short*)(ws + (3u << 20));       // 1 MB
  unsigned short* v5   = (unsigned short*)(ws + (4u << 20));       // 8 MB

  proj_kernel<<<256, 256, 0, stream>>>(x, Wq, bq, Wk, bk, Wv, bv, qh, ql, kh, kl, v5);
  attn_pv_kernel<<<1024, 256, 0, stream>>>(qh, ql, kh, kl, v5, x, gamma, out);
}

// Round 7
// 165.632 us; speedup vs baseline: 1.2962x; 1.2962x over previous
//
#include <hip/hip_runtime.h>
#include <stdint.h>

#define CC 256
#define NNq 4096

typedef float f32x4 __attribute__((ext_vector_type(4)));
typedef short bf16x8 __attribute__((ext_vector_type(8)));

#define MFMA16(a, b, c) __builtin_amdgcn_mfma_f32_16x16x32_bf16(a, b, c, 0, 0, 0)

static __device__ __forceinline__ short f2bf(float f) {
  unsigned u = __builtin_bit_cast(unsigned, f);
  u += 0x7fffu + ((u >> 16) & 1u);   // RNE
  return (short)(u >> 16);
}
static __device__ __forceinline__ float bf2f(short s) {
  return __builtin_bit_cast(float, ((unsigned)(unsigned short)s) << 16);
}

// barrier that does NOT drain vmcnt (prefetch + stores stay in flight);
// sched_barrier(0) fences compile-time motion across it (rule 18).
#define SBAR() do { \
  __builtin_amdgcn_sched_barrier(0); \
  asm volatile("s_waitcnt lgkmcnt(0)" ::: "memory"); \
  __builtin_amdgcn_s_barrier(); \
  __builtin_amdgcn_sched_barrier(0); \
} while (0)

// ---------------------------------------------------------------------------
// Kernel 1: projections.
//  - q,k: split hi/lo bf16, separate arrays [B][N][32]; q pre-scaled by log2e.
//  - v: bf16 pre-tiled as MFMA A-fragments: v5[b][m>>5][c][m&31]
//    -> PV fragment loads are 1KB fully contiguous.
// ---------------------------------------------------------------------------
#define XSTR 66

__global__ __launch_bounds__(256) void proj_kernel(
    const float* __restrict__ x,
    const float* __restrict__ Wq, const float* __restrict__ bq,
    const float* __restrict__ Wk, const float* __restrict__ bk,
    const float* __restrict__ Wv, const float* __restrict__ bv,
    unsigned short* __restrict__ qh_, unsigned short* __restrict__ ql_,
    unsigned short* __restrict__ kh_, unsigned short* __restrict__ kl_,
    unsigned short* __restrict__ v5)
{
  __shared__ float xs[256 * XSTR];
  const int t = threadIdx.x;
  const int b = blockIdx.x >> 6;
  const int n0 = (blockIdx.x & 63) << 6;
  const float L2E = 1.4426950408889634f;

  const float* xb = x + ((size_t)b * CC) * NNq + n0;
#pragma unroll
  for (int i = 0; i < 16; ++i) {
    int fi = i * 256 + t;
    int c = fi >> 4, nv = (fi & 15) << 2;
    float4 v4 = *(const float4*)(xb + (size_t)c * NNq + nv);
    float* d = &xs[c * XSTR + nv];
    d[0] = v4.x; d[1] = v4.y; d[2] = v4.z; d[3] = v4.w;
  }
  __syncthreads();

  const int w = t >> 6, l = t & 63;
  const int l15 = l & 15, l4 = l >> 4;

  // 20 row-tiles: 16 v + 2 q + 2 k ; wave w owns tiles w*5 .. w*5+4
  f32x4 acc[5][4];
#pragma unroll
  for (int r5 = 0; r5 < 5; ++r5) {
    int rt = w * 5 + r5;
    const float* bias; float bscale;
    if (rt < 16)      { bias = bv + rt * 16;        bscale = 1.f; }
    else if (rt < 18) { bias = bq + (rt - 16) * 16; bscale = L2E; }
    else              { bias = bk + (rt - 18) * 16; bscale = 1.f; }
#pragma unroll
    for (int j = 0; j < 4; ++j) {
      float bval = bias[l4 * 4 + j] * bscale;
#pragma unroll
      for (int nt = 0; nt < 4; ++nt) acc[r5][nt][j] = bval;
    }
  }

#pragma unroll 1
  for (int ks = 0; ks < 8; ++ks) {
    bf16x8 ah[5], al[5];
#pragma unroll
    for (int r5 = 0; r5 < 5; ++r5) {
      int rt = w * 5 + r5;
      const float* wrow; float wscale;
      if (rt < 16)      { wrow = Wv + (size_t)(rt * 16 + l15) * 256;        wscale = 1.f; }
      else if (rt < 18) { wrow = Wq + (size_t)((rt - 16) * 16 + l15) * 256; wscale = L2E; }
      else              { wrow = Wk + (size_t)((rt - 18) * 16 + l15) * 256; wscale = 1.f; }
      const float* src = wrow + ks * 32 + l4 * 8;
#pragma unroll
      for (int i = 0; i < 8; ++i) {
        float v = src[i] * wscale;
        short hh = f2bf(v);
        ah[r5][i] = hh;
        al[r5][i] = f2bf(v - bf2f(hh));
      }
    }
#pragma unroll
    for (int nt = 0; nt < 4; ++nt) {
      bf16x8 bh, bl;
#pragma unroll
      for (int i = 0; i < 8; ++i) {
        float v = xs[(ks * 32 + l4 * 8 + i) * XSTR + nt * 16 + l15];
        short hh = f2bf(v);
        bh[i] = hh;
        bl[i] = f2bf(v - bf2f(hh));
      }
#pragma unroll
      for (int r5 = 0; r5 < 5; ++r5) {
        acc[r5][nt] = MFMA16(ah[r5], bl, acc[r5][nt]);
        acc[r5][nt] = MFMA16(al[r5], bh, acc[r5][nt]);
        acc[r5][nt] = MFMA16(ah[r5], bh, acc[r5][nt]);
      }
    }
  }

#pragma unroll
  for (int r5 = 0; r5 < 5; ++r5) {
    int rt = w * 5 + r5;
#pragma unroll
    for (int nt = 0; nt < 4; ++nt) {
      int n = n0 + nt * 16 + l15;
#pragma unroll
      for (int j = 0; j < 4; ++j) {
        float v = acc[r5][nt][j];
        int sub = l4 * 4 + j;
        if (rt < 16) {
          int c = rt * 16 + sub;
          // v5[b][n>>5][c][n&31]
          size_t o = (((size_t)b * 128 + (n >> 5)) * 256 + c) * 32 + (n & 31);
          v5[o] = (unsigned short)f2bf(v);
        } else {
          short hh = f2bf(v);
          short lo = f2bf(v - bf2f(hh));
          unsigned short* dh = (rt < 18) ? qh_ : kh_;
          unsigned short* dl = (rt < 18) ? ql_ : kl_;
          int d = ((rt < 18) ? (rt - 16) : (rt - 18)) * 16 + sub;
          size_t o = ((size_t)b * NNq + n) * 32 + d;
          dh[o] = (unsigned short)hh;
          dl[o] = (unsigned short)lo;
        }
      }
    }
  }
}

// ---------------------------------------------------------------------------
// Kernel 2: fused stats + attention write + PV + epilogue.
// Block = 512 threads (8 waves) owns (b, 32 rows). Grid 512 = 2 blocks/CU
// (r5 structure — best measured). Changes vs r5:
//  - pass 1: wave owns a 512-m slice, computes BOTH row groups per k frag
//    (24 MFMA per 8 k-loads in flight; k traffic halved, 2x ILP)
//  - pass 2: chunk 128 m (half the barriers, double work per window:
//    6 E-MFMA + 16 PV-MFMA + 8 contiguous-1KB v loads per wave)
//  - setprio(1) around the PV MFMA cluster (T5)
// vmcnt never drained; double-buffered swizzled p tile, one SBAR per chunk.
// ---------------------------------------------------------------------------
__global__ __launch_bounds__(512, 4) void attn_pv_kernel(
    const unsigned short* __restrict__ qh_, const unsigned short* __restrict__ ql_,
    const unsigned short* __restrict__ kh_, const unsigned short* __restrict__ kl_,
    const unsigned short* __restrict__ v5, const float* __restrict__ x,
    const float* __restrict__ gamma, float* __restrict__ out)
{
  __shared__ __align__(16) unsigned short p_lds[2][4096]; // [par][32 n][128 m] bf16, XOR-swz
  __shared__ float sums_lds[8][32];

  const int t = threadIdx.x, w = t >> 6, l = t & 63;
  const int l15 = l & 15, l4 = l >> 4;
  // XCD swizzle: 512 blocks (512%8==0, bijective)
  const int sb = ((blockIdx.x & 7) << 6) | (blockIdx.x >> 3);
  const int b = sb >> 7;
  const int n0 = (sb & 127) << 5;
  const int g = w >> 2, h = w & 3;      // pass-2 roles: row-group, m-slice

  const unsigned short* khb = kh_ + (size_t)b * NNq * 32;
  const unsigned short* klb = kl_ + (size_t)b * NNq * 32;
  const unsigned short* vbb = v5 + (size_t)b * 1048576;
  float* attn = out + 8388608 + (size_t)b * NNq * NNq + (size_t)n0 * NNq;

  // q fragments for both row groups (pass 1 needs both; pass 2 keeps own g)
  bf16x8 q2h[2], q2l[2];
#pragma unroll
  for (int rg = 0; rg < 2; ++rg) {
    size_t qo = ((size_t)b * NNq + n0 + rg * 16 + l15) * 32 + l4 * 8;
    q2h[rg] = *(const bf16x8*)(qh_ + qo);
    q2l[rg] = *(const bf16x8*)(ql_ + qo);
  }

  // ---------------- pass 1: row sums; wave owns m in [w*512, w*512+512) -----
  float sx[2][4] = {{0.f,0.f,0.f,0.f},{0.f,0.f,0.f,0.f}};
  {
    const int mq = w * 512;
    bf16x8 kch[2], kcl[2];
#pragma unroll
    for (int mt = 0; mt < 2; ++mt) {
      size_t ko = (size_t)(mq + mt * 16 + l15) * 32 + l4 * 8;
      kch[mt] = *(const bf16x8*)(khb + ko);
      kcl[mt] = *(const bf16x8*)(klb + ko);
    }
#pragma unroll 1
    for (int it = 0; it < 16; ++it) {
      const int nx = mq + ((it + 1) & 15) * 32;
      bf16x8 knh[2], knl[2];
#pragma unroll
      for (int mt = 0; mt < 2; ++mt) {
        size_t ko = (size_t)(nx + mt * 16 + l15) * 32 + l4 * 8;
        knh[mt] = *(const bf16x8*)(khb + ko);
        knl[mt] = *(const bf16x8*)(klb + ko);
      }
#pragma unroll
      for (int mt = 0; mt < 2; ++mt) {
#pragma unroll
        for (int rg = 0; rg < 2; ++rg) {
          f32x4 e = {0.f, 0.f, 0.f, 0.f};
          e = MFMA16(q2h[rg], kcl[mt], e);
          e = MFMA16(q2l[rg], kch[mt], e);
          e = MFMA16(q2h[rg], kch[mt], e);
#pragma unroll
          for (int j = 0; j < 4; ++j) sx[rg][j] += exp2f(e[j] - 64.0f);
        }
      }
      kch[0] = knh[0]; kch[1] = knh[1];
      kcl[0] = knl[0]; kcl[1] = knl[1];
    }
  }
#pragma unroll
  for (int mask = 1; mask < 16; mask <<= 1)
#pragma unroll
    for (int rg = 0; rg < 2; ++rg)
#pragma unroll
      for (int j = 0; j < 4; ++j) sx[rg][j] += __shfl_xor(sx[rg][j], mask);
  if (l15 == 0) {
#pragma unroll
    for (int rg = 0; rg < 2; ++rg)
#pragma unroll
      for (int j = 0; j < 4; ++j)
        sums_lds[w][rg * 16 + l4 * 4 + j] = sx[rg][j];
  }
  __syncthreads();
  const bf16x8 qh = q2h[g], qlo = q2l[g];
  f32x4 crow;
#pragma unroll
  for (int j = 0; j < 4; ++j) {
    int r = g * 16 + l4 * 4 + j;
    float S = 0.f;
#pragma unroll
    for (int ww = 0; ww < 8; ++ww) S += sums_lds[ww][r];
    crow[j] = 64.0f + log2f(S);
  }

  // ---------------- pass 2: attention + PV, 128-m chunks ----------------
  f32x4 acc[2][2];   // c = w*32 + ct*16 + l4*4 + j ; n = n0 + nt*16 + l15
#pragma unroll
  for (int ct = 0; ct < 2; ++ct)
#pragma unroll
    for (int nt = 0; nt < 2; ++nt) acc[ct][nt] = f32x4{0.f, 0.f, 0.f, 0.f};

  // k fragments for chunk 0 (m = h*32 + {0,16})
  bf16x8 kch[2], kcl[2];
#pragma unroll
  for (int sub = 0; sub < 2; ++sub) {
    size_t ko = (size_t)(h * 32 + sub * 16 + l15) * 32 + l4 * 8;
    kch[sub] = *(const bf16x8*)(khb + ko);
    kcl[sub] = *(const bf16x8*)(klb + ko);
  }

#pragma unroll 1
  for (int it = 0; it < 32; ++it) {
    const int mb = it * 128;
    char* pl = (char*)p_lds[it & 1];
    // v fragments for THIS chunk (8 x contiguous 1KB), issued early,
    // consumed after the barrier (E+exp hides L2 latency)
    bf16x8 vf[2][4];
#pragma unroll
    for (int ct = 0; ct < 2; ++ct)
#pragma unroll
      for (int ms = 0; ms < 4; ++ms) {
        size_t vo = (size_t)(it * 4 + ms) * 8192 +
                    (size_t)(w * 32 + ct * 16 + l15) * 32 + l4 * 8;
        vf[ct][ms] = *(const bf16x8*)(vbb + vo);
      }
    // next-chunk k prefetch (stays in flight across the barrier)
    const int nxb = ((it + 1) & 31) * 128;
    bf16x8 knh[2], knl[2];
#pragma unroll
    for (int sub = 0; sub < 2; ++sub) {
      size_t ko = (size_t)(nxb + h * 32 + sub * 16 + l15) * 32 + l4 * 8;
      knh[sub] = *(const bf16x8*)(khb + ko);
      knl[sub] = *(const bf16x8*)(klb + ko);
    }
    // E phase: 2 sub-tiles -> p -> attn store (from regs) + swizzled LDS
#pragma unroll
    for (int sub = 0; sub < 2; ++sub) {
      f32x4 e = {0.f, 0.f, 0.f, 0.f};
      e = MFMA16(qh, kcl[sub], e);
      e = MFMA16(qlo, kch[sub], e);
      e = MFMA16(qh, kch[sub], e);
#pragma unroll
      for (int j = 0; j < 4; ++j) {
        float p = exp2f(e[j] - crow[j]);
        int nl = g * 16 + l4 * 4 + j;          // row within 32-tile
        int ml = h * 32 + sub * 16 + l15;      // m within 128-chunk
        attn[(size_t)nl * NNq + mb + ml] = p;
        int byteo = nl * 256 + ((ml * 2) ^ ((nl & 7) << 4));
        *(unsigned short*)(pl + byteo) = (unsigned short)f2bf(p);
      }
    }
    SBAR();
    // PV: A = v frags (regs), B = p frags from LDS (transpose read)
    __builtin_amdgcn_s_setprio(1);
#pragma unroll
    for (int ms = 0; ms < 4; ++ms) {
      int mbyte = ms * 64 + l4 * 16;
      bf16x8 pf0, pf1;
      {
        int nl0 = l15,      o0 = nl0 * 256 + (mbyte ^ ((nl0 & 7) << 4));
        int nl1 = 16 + l15, o1 = nl1 * 256 + (mbyte ^ ((nl1 & 7) << 4));
        pf0 = *(const bf16x8*)(pl + o0);
        pf1 = *(const bf16x8*)(pl + o1);
      }
#pragma unroll
      for (int ct = 0; ct < 2; ++ct) {
        acc[ct][0] = MFMA16(vf[ct][ms], pf0, acc[ct][0]);
        acc[ct][1] = MFMA16(vf[ct][ms], pf1, acc[ct][1]);
      }
    }
    __builtin_amdgcn_s_setprio(0);
    kch[0] = knh[0]; kch[1] = knh[1];
    kcl[0] = knl[0]; kcl[1] = knl[1];
  }

  // epilogue: weighted = gamma*pv ; final = weighted + x
  const float gm = gamma[0];
#pragma unroll
  for (int ct = 0; ct < 2; ++ct) {
#pragma unroll
    for (int nt = 0; nt < 2; ++nt) {
#pragma unroll
      for (int j = 0; j < 4; ++j) {
        int c = w * 32 + ct * 16 + l4 * 4 + j;
        int n = n0 + nt * 16 + l15;
        size_t go = ((size_t)b * CC + c) * NNq + n;
        float o = acc[ct][nt][j] * gm;
        out[4194304 + go] = o;
        out[go] = o + x[go];
      }
    }
  }
}

extern "C" void kernel_launch(void* const* d_in, const int* in_sizes, int n_in,
                              void* d_out, int out_size, void* d_ws, size_t ws_size,
                              hipStream_t stream) {
  const float* x     = (const float*)d_in[0];
  const float* Wq    = (const float*)d_in[1];
  const float* bq    = (const float*)d_in[2];
  const float* Wk    = (const float*)d_in[3];
  const float* bk    = (const float*)d_in[4];
  const float* Wv    = (const float*)d_in[5];
  const float* bv    = (const float*)d_in[6];
  const float* gamma = (const float*)d_in[7];
  float* out = (float*)d_out;

  char* ws = (char*)d_ws;
  unsigned short* qh   = (unsigned short*)(ws);                    // 1 MB
  unsigned short* ql   = (unsigned short*)(ws + (1u << 20));       // 1 MB
  unsigned short* kh   = (unsigned short*)(ws + (2u << 20));       // 1 MB
  unsigned short* kl   = (unsigned short*)(ws + (3u << 20));       // 1 MB
  unsigned short* v5   = (unsigned short*)(ws + (4u << 20));       // 8 MB

  proj_kernel<<<256, 256, 0, stream>>>(x, Wq, bq, Wk, bk, Wv, bv, qh, ql, kh, kl, v5);
  attn_pv_kernel<<<512, 512, 0, stream>>>(qh, ql, kh, kl, v5, x, gamma, out);
}